// Round 1
// baseline (292.163 us; speedup 1.0000x reference)
//
#include <hip/hip_runtime.h>
#include <math.h>

#ifndef M_PI
#define M_PI 3.14159265358979323846
#endif

#define BB 8
#define LL 4096
#define DD 256
#define HH 64

__device__ __forceinline__ float2 cmulf(float2 a, float2 b) {
    return make_float2(a.x*b.x - a.y*b.y, a.x*b.y + a.y*b.x);
}

__device__ __forceinline__ int rev6(int x) {
    return (int)(__brev((unsigned)x) >> 26);
}

// 64-point FFT across the 64 lanes of a wave. DIF radix-2, 6 shuffle stages.
// Input: natural order (lane = index). Output: value at lane l is X[rev6(l)].
// twc/tws: per-lane stage twiddles for FORWARD direction (angle = -pi*j/m).
template<bool INV>
__device__ __forceinline__ float2 fft64(float2 v, int lane, const float* twc, const float* tws) {
#pragma unroll
    for (int s = 0; s < 6; ++s) {
        const int m = 32 >> s;
        float ox = __shfl_xor(v.x, m, 64);
        float oy = __shfl_xor(v.y, m, 64);
        const bool up = (lane & m) != 0;
        float sx = up ? (ox - v.x) : (v.x + ox);
        float sy = up ? (oy - v.y) : (v.y + oy);
        const float c  = twc[s];
        const float sn = INV ? -tws[s] : tws[s];
        float rx = sx*c - sy*sn;
        float ry = sx*sn + sy*c;
        v.x = up ? rx : sx;
        v.y = up ? ry : sy;
    }
    return v;
}

__device__ __forceinline__ float2 woodbury_coef(
    float k00r, float k00i, float k01r, float k01i,
    float k10r, float k10i, float k11r, float k11i, float tc)
{
    // res = k00 - k01*k10/(1+k11);  return (1 + i*tc) * res
    float wr = 1.f + k11r, wi = k11i;
    float winv = 1.f / (wr*wr + wi*wi);
    float qr = k01r*k10r - k01i*k10i;
    float qi = k01r*k10i + k01i*k10r;
    float dr = (qr*wr + qi*wi) * winv;
    float di = (qi*wr - qr*wi) * winv;
    float rr = k00r - dr, ri = k00i - di;
    return make_float2(rr - tc*ri, tc*rr + ri);
}

// ---------------------------------------------------------------------------
// Kernel 1: Cauchy dot products + Woodbury -> Kf spectrum, written in the
// four-step "matrix" layout: Kf_mat[d][ (l&63)*64 + (l>>6) ] = Kf[d][l].
// Thread l in [0,2048] computes at_roots(l) and at_roots(L-l) together
// (t -> -t), combines to Kf[l] = 0.5*(ar_l + conj(ar_{L-l})), Kf[L-l]=conj.
// ---------------------------------------------------------------------------
__global__ __launch_bounds__(256)
void s4_cauchy_kf(const float* __restrict__ lam_ri,
                  const float* __restrict__ P_ri,
                  const float* __restrict__ B_ri,
                  const float* __restrict__ C_ri,
                  const float* __restrict__ log_delta,
                  float2* __restrict__ Kf)
{
    __shared__ float w00r[HH], w00i[HH], w01r[HH], w01i[HH],
                     w10r[HH], w10i[HH], w11s[HH], lre[HH], lim[HH];
    const int d   = blockIdx.y;
    const int tid = threadIdx.x;
    if (tid < HH) {
        const int h = tid;
        float br = B_ri[(d*HH + h)*2 + 0], bi = B_ri[(d*HH + h)*2 + 1];
        float cr = C_ri[(d*HH + h)*2 + 0], ci = C_ri[(d*HH + h)*2 + 1];
        float pr = P_ri[h*2 + 0], pi = P_ri[h*2 + 1];
        w00r[h] = cr*br - ci*bi;   w00i[h] = cr*bi + ci*br;   // C*B
        w01r[h] = cr*pr - ci*pi;   w01i[h] = cr*pi + ci*pr;   // C*P
        w10r[h] = pr*br + pi*bi;   w10i[h] = pr*bi - pi*br;   // conj(P)*B
        w11s[h] = pr*pr + pi*pi;                              // conj(P)*P (real)
        lre[h]  = lam_ri[h*2+0];   lim[h]  = lam_ri[h*2+1];
    }
    __syncthreads();
    const int l = blockIdx.x * blockDim.x + tid;
    if (l > 2048) return;
    const float delta = expf(log_delta[d]);

    if (l == 2048) {
        // analytic limit at z=-1: at_roots = (delta/2) * sum(C*B); Kf real part
        float sr = 0.f, si = 0.f;
        for (int h = 0; h < HH; ++h) { sr += w00r[h]; si += w00i[h]; }
        (void)si;
        Kf[(size_t)d*LL + ((2048 & 63)*64 + (2048 >> 6))] = make_float2(0.5f*delta*sr, 0.f);
        return;
    }

    const double th = (double)l * (M_PI / 4096.0);
    const float  t  = (float)tan(th);           // tan(theta/2), theta = 2*pi*l/L
    const float  G  = -2.f * t / delta;         // g = i*G  (purely imaginary)

    float a00r=0,a00i=0,a01r=0,a01i=0,a10r=0,a10i=0,a11r=0,a11i=0;  // l
    float b00r=0,b00i=0,b01r=0,b01i=0,b10r=0,b10i=0,b11r=0,b11i=0;  // L-l

    for (int h = 0; h < HH; ++h) {
        const float nr  = -lre[h];
        const float lih = lim[h];
        const float W00r = w00r[h], W00i = w00i[h];
        const float W01r = w01r[h], W01i = w01i[h];
        const float W10r = w10r[h], W10i = w10i[h];
        const float W11  = w11s[h];
        {
            const float ni  = G - lih;
            const float inv = 1.f / (nr*nr + ni*ni);
            const float rr  = nr*inv, ri = -ni*inv;   // 1/(g - lam)
            a00r += W00r*rr - W00i*ri;  a00i += W00r*ri + W00i*rr;
            a01r += W01r*rr - W01i*ri;  a01i += W01r*ri + W01i*rr;
            a10r += W10r*rr - W10i*ri;  a10i += W10r*ri + W10i*rr;
            a11r += W11*rr;             a11i += W11*ri;
        }
        {
            const float ni  = -G - lih;
            const float inv = 1.f / (nr*nr + ni*ni);
            const float rr  = nr*inv, ri = -ni*inv;
            b00r += W00r*rr - W00i*ri;  b00i += W00r*ri + W00i*rr;
            b01r += W01r*rr - W01i*ri;  b01i += W01r*ri + W01i*rr;
            b10r += W10r*rr - W10i*ri;  b10i += W10r*ri + W10i*rr;
            b11r += W11*rr;             b11i += W11*ri;
        }
    }

    // coef = 1 - i*t for l ; 1 + i*t for L-l
    float2 ar1 = woodbury_coef(a00r,a00i,a01r,a01i,a10r,a10i,a11r,a11i, -t);
    float2 ar2 = woodbury_coef(b00r,b00i,b01r,b01i,b10r,b10i,b11r,b11i, +t);

    float2 kf = make_float2(0.5f*(ar1.x + ar2.x), 0.5f*(ar1.y - ar2.y));
    const int e1 = (l & 63)*64 + (l >> 6);
    Kf[(size_t)d*LL + e1] = kf;
    if (l > 0) {
        const int lp = LL - l;
        const int e2 = (lp & 63)*64 + (lp >> 6);
        Kf[(size_t)d*LL + e2] = make_float2(kf.x, -kf.y);
    }
}

// ---------------------------------------------------------------------------
// Kernel T1: x (B,L,D) -> xt (B,D,L), tiled transpose.
// ---------------------------------------------------------------------------
__global__ __launch_bounds__(256)
void s4_transpose_fwd(const float* __restrict__ x, float* __restrict__ xt)
{
    __shared__ float tile[64][65];
    const int b  = blockIdx.z;
    const int l0 = blockIdx.x * 64;
    const int d0 = blockIdx.y * 64;
    const int tc = threadIdx.x & 63;
    const int tr = threadIdx.x >> 6;
#pragma unroll
    for (int i = 0; i < 16; ++i) {
        int row = tr + 4*i;   // l offset
        tile[row][tc] = x[((size_t)b*LL + (l0+row))*DD + d0 + tc];
    }
    __syncthreads();
#pragma unroll
    for (int i = 0; i < 16; ++i) {
        int row = tr + 4*i;   // d offset
        xt[((size_t)b*DD + (d0+row))*LL + l0 + tc] = tile[tc][row];
    }
}

// ---------------------------------------------------------------------------
// Kernel 2: per (b,d) column: forward FFT-4096 (four-step 64x64), multiply by
// Kf, inverse FFT, write real part back in place. Data lives in LDS.
// ---------------------------------------------------------------------------
__global__ __launch_bounds__(256)
void s4_fftconv(float* __restrict__ xt, const float2* __restrict__ Kf)
{
    __shared__ float2 A[64][65];
    const int tid  = threadIdx.x;
    const int lane = tid & 63;
    const int wid  = tid >> 6;
    const int d    = blockIdx.x & (DD-1);
    const int b    = blockIdx.x >> 8;
    float* colp = xt + ((size_t)b*DD + d)*LL;

    // per-lane stage twiddles (forward): W_{2m}^{j} = exp(-i*pi*j/m), j = lane&(m-1)
    float twc[6], tws[6];
#pragma unroll
    for (int s = 0; s < 6; ++s) {
        int m = 32 >> s;
        int j = lane & (m-1);
        float ang = -(float)M_PI * (float)j / (float)m;
        sincosf(ang, &tws[s], &twc[s]);
    }

    // load column (real -> complex); n = n1*64 + n2 stored at A[n1][n2]
#pragma unroll
    for (int i = 0; i < 16; ++i) {
        int n = tid + 256*i;
        A[n>>6][n&63] = make_float2(colp[n], 0.f);
    }
    __syncthreads();

    // forward: column FFTs over n1 (lane = row)
    for (int c = 0; c < 16; ++c) {
        int col = wid*16 + c;
        float2 v = A[lane][col];
        v = fft64<false>(v, lane, twc, tws);
        A[rev6(lane)][col] = v;
    }
    __syncthreads();

    // twiddle W_4096^{-k1*n2} at [k1][n2]
    const float TW = -(float)(2.0*M_PI/4096.0);
#pragma unroll
    for (int i = 0; i < 16; ++i) {
        int e = tid + 256*i;
        int r = e>>6, c = e&63;
        float sn, cs; sincosf(TW * (float)(r*c), &sn, &cs);
        A[r][c] = cmulf(A[r][c], make_float2(cs, sn));
    }
    __syncthreads();

    // forward: row FFTs over n2 (lane = col)  -> X[k1 + 64*k2] at A[k1][k2]
    for (int c = 0; c < 16; ++c) {
        int row = wid*16 + c;
        float2 v = A[row][lane];
        v = fft64<false>(v, lane, twc, tws);
        A[row][rev6(lane)] = v;
    }
    __syncthreads();

    // pointwise multiply by Kf (stored in matching matrix layout)
    const float2* Kfd = Kf + (size_t)d*LL;
#pragma unroll
    for (int i = 0; i < 16; ++i) {
        int e = tid + 256*i;
        float2 kv = Kfd[e];
        A[e>>6][e&63] = cmulf(A[e>>6][e&63], kv);
    }
    __syncthreads();

    // inverse: row FFTs over k2
    for (int c = 0; c < 16; ++c) {
        int row = wid*16 + c;
        float2 v = A[row][lane];
        v = fft64<true>(v, lane, twc, tws);
        A[row][rev6(lane)] = v;
    }
    __syncthreads();

    // twiddle W_4096^{+k1*n2}
#pragma unroll
    for (int i = 0; i < 16; ++i) {
        int e = tid + 256*i;
        int r = e>>6, c = e&63;
        float sn, cs; sincosf(-TW * (float)(r*c), &sn, &cs);
        A[r][c] = cmulf(A[r][c], make_float2(cs, sn));
    }
    __syncthreads();

    // inverse: column FFTs over k1 -> time sample n at A[n>>6][n&63]
    for (int c = 0; c < 16; ++c) {
        int col = wid*16 + c;
        float2 v = A[lane][col];
        v = fft64<true>(v, lane, twc, tws);
        A[rev6(lane)][col] = v;
    }
    __syncthreads();

    const float scale = 1.f/4096.f;
#pragma unroll
    for (int i = 0; i < 16; ++i) {
        int n = tid + 256*i;
        colp[n] = A[n>>6][n&63].x * scale;
    }
}

// ---------------------------------------------------------------------------
// Kernel T2: y (B,L,D) = yt (B,D,L) transposed back + D * x
// ---------------------------------------------------------------------------
__global__ __launch_bounds__(256)
void s4_transpose_add(const float* __restrict__ yt, const float* __restrict__ x,
                      const float* __restrict__ Dp, float* __restrict__ y)
{
    __shared__ float tile[64][65];
    const int b  = blockIdx.z;
    const int l0 = blockIdx.x * 64;
    const int d0 = blockIdx.y * 64;
    const int tc = threadIdx.x & 63;
    const int tr = threadIdx.x >> 6;
#pragma unroll
    for (int i = 0; i < 16; ++i) {
        int drow = tr + 4*i;
        tile[drow][tc] = yt[((size_t)b*DD + (d0+drow))*LL + l0 + tc];
    }
    __syncthreads();
    const float dval = Dp[d0 + tc];
#pragma unroll
    for (int i = 0; i < 16; ++i) {
        int lrow = tr + 4*i;
        size_t idx = ((size_t)b*LL + (l0+lrow))*DD + d0 + tc;
        y[idx] = tile[tc][lrow] + dval * x[idx];
    }
}

extern "C" void kernel_launch(void* const* d_in, const int* in_sizes, int n_in,
                              void* d_out, int out_size, void* d_ws, size_t ws_size,
                              hipStream_t stream)
{
    (void)in_sizes; (void)n_in; (void)out_size; (void)ws_size;
    const float* x         = (const float*)d_in[0];
    const float* lam_ri    = (const float*)d_in[1];
    const float* P_ri      = (const float*)d_in[2];
    const float* B_ri      = (const float*)d_in[3];
    const float* C_ri      = (const float*)d_in[4];
    const float* Dp        = (const float*)d_in[5];
    const float* log_delta = (const float*)d_in[6];
    float* y = (float*)d_out;

    float2* Kf = (float2*)d_ws;                                          // 8 MB
    float*  xt = (float*)((char*)d_ws + (size_t)DD*LL*sizeof(float2));   // 32 MB

    s4_cauchy_kf<<<dim3(9, DD), 256, 0, stream>>>(lam_ri, P_ri, B_ri, C_ri, log_delta, Kf);
    s4_transpose_fwd<<<dim3(LL/64, DD/64, BB), 256, 0, stream>>>(x, xt);
    s4_fftconv<<<dim3(BB*DD), 256, 0, stream>>>(xt, Kf);
    s4_transpose_add<<<dim3(LL/64, DD/64, BB), 256, 0, stream>>>(xt, x, Dp, y);
}

// Round 2
// 205.262 us; speedup vs baseline: 1.4234x; 1.4234x over previous
//
#include <hip/hip_runtime.h>
#include <math.h>

#ifndef M_PI
#define M_PI 3.14159265358979323846
#endif

#define BB 8
#define LL 4096
#define DD 256
#define HH 64

__device__ __forceinline__ float2 cmulf(float2 a, float2 b) {
    return make_float2(a.x*b.x - a.y*b.y, a.x*b.y + a.y*b.x);
}

__device__ __forceinline__ int rev6(int x) {
    return (int)(__brev((unsigned)x) >> 26);
}

// 64-point FFT across the 64 lanes of a wave. DIF radix-2, 6 shuffle stages.
// Input: natural order (lane = index). Output: value at lane l is X[rev6(l)].
template<bool INV>
__device__ __forceinline__ float2 fft64(float2 v, int lane, const float* twc, const float* tws) {
#pragma unroll
    for (int s = 0; s < 6; ++s) {
        const int m = 32 >> s;
        float ox = __shfl_xor(v.x, m, 64);
        float oy = __shfl_xor(v.y, m, 64);
        const bool up = (lane & m) != 0;
        float sx = up ? (ox - v.x) : (v.x + ox);
        float sy = up ? (oy - v.y) : (v.y + oy);
        const float c  = twc[s];
        const float sn = INV ? -tws[s] : tws[s];
        float rx = sx*c - sy*sn;
        float ry = sx*sn + sy*c;
        v.x = up ? rx : sx;
        v.y = up ? ry : sy;
    }
    return v;
}

__device__ __forceinline__ float2 woodbury_coef(
    float k00r, float k00i, float k01r, float k01i,
    float k10r, float k10i, float k11r, float k11i, float tc)
{
    // res = k00 - k01*k10/(1+k11);  return (1 + i*tc) * res
    float wr = 1.f + k11r, wi = k11i;
    float winv = 1.f / (wr*wr + wi*wi);
    float qr = k01r*k10r - k01i*k10i;
    float qi = k01r*k10i + k01i*k10r;
    float dr = (qr*wr + qi*wi) * winv;
    float di = (qi*wr - qr*wi) * winv;
    float rr = k00r - dr, ri = k00i - di;
    return make_float2(rr - tc*ri, tc*rr + ri);
}

// ---------------------------------------------------------------------------
// Kernel 1: Cauchy + Woodbury -> Kf spectrum (lower half only, k in [0,2048]),
// matrix layout Kf[d][k1*64 + k2] for k = k1 + 64*k2. D-term folded in:
// Kf += Dp[d] (delta-kernel spectrum is the constant D).
// ---------------------------------------------------------------------------
__global__ __launch_bounds__(256)
void s4_cauchy_kf(const float* __restrict__ lam_ri,
                  const float* __restrict__ P_ri,
                  const float* __restrict__ B_ri,
                  const float* __restrict__ C_ri,
                  const float* __restrict__ Dp,
                  const float* __restrict__ log_delta,
                  float2* __restrict__ Kf)
{
    __shared__ float w00r[HH], w00i[HH], w01r[HH], w01i[HH],
                     w10r[HH], w10i[HH], w11s[HH], lre[HH], lim[HH];
    const int d   = blockIdx.y;
    const int tid = threadIdx.x;
    if (tid < HH) {
        const int h = tid;
        float br = B_ri[(d*HH + h)*2 + 0], bi = B_ri[(d*HH + h)*2 + 1];
        float cr = C_ri[(d*HH + h)*2 + 0], ci = C_ri[(d*HH + h)*2 + 1];
        float pr = P_ri[h*2 + 0], pi = P_ri[h*2 + 1];
        w00r[h] = cr*br - ci*bi;   w00i[h] = cr*bi + ci*br;   // C*B
        w01r[h] = cr*pr - ci*pi;   w01i[h] = cr*pi + ci*pr;   // C*P
        w10r[h] = pr*br + pi*bi;   w10i[h] = pr*bi - pi*br;   // conj(P)*B
        w11s[h] = pr*pr + pi*pi;                              // conj(P)*P (real)
        lre[h]  = lam_ri[h*2+0];   lim[h]  = lam_ri[h*2+1];
    }
    __syncthreads();
    const int l = blockIdx.x * blockDim.x + tid;
    if (l > 2048) return;
    const float delta = expf(log_delta[d]);
    const float dterm = Dp[d];

    if (l == 2048) {
        // analytic limit at z=-1: at_roots = (delta/2) * sum(C*B), real part
        float sr = 0.f;
        for (int h = 0; h < HH; ++h) sr += w00r[h];
        Kf[(size_t)d*LL + (0*64 + 32)] = make_float2(0.5f*delta*sr + dterm, 0.f);
        return;
    }

    float sn, cs;
    sincosf((float)l * (float)(M_PI/4096.0), &sn, &cs);
    const float t = sn / cs;                    // tan(theta/2), theta = 2*pi*l/L
    const float G = -2.f * t / delta;           // g = i*G (purely imaginary)

    float a00r=0,a00i=0,a01r=0,a01i=0,a10r=0,a10i=0,a11r=0,a11i=0;  // l
    float b00r=0,b00i=0,b01r=0,b01i=0,b10r=0,b10i=0,b11r=0,b11i=0;  // L-l

    for (int h = 0; h < HH; ++h) {
        const float nr  = -lre[h];
        const float lih = lim[h];
        const float W00r = w00r[h], W00i = w00i[h];
        const float W01r = w01r[h], W01i = w01i[h];
        const float W10r = w10r[h], W10i = w10i[h];
        const float W11  = w11s[h];
        {
            const float ni  = G - lih;
            const float inv = 1.f / (nr*nr + ni*ni);
            const float rr  = nr*inv, ri = -ni*inv;   // 1/(g - lam)
            a00r += W00r*rr - W00i*ri;  a00i += W00r*ri + W00i*rr;
            a01r += W01r*rr - W01i*ri;  a01i += W01r*ri + W01i*rr;
            a10r += W10r*rr - W10i*ri;  a10i += W10r*ri + W10i*rr;
            a11r += W11*rr;             a11i += W11*ri;
        }
        {
            const float ni  = -G - lih;
            const float inv = 1.f / (nr*nr + ni*ni);
            const float rr  = nr*inv, ri = -ni*inv;
            b00r += W00r*rr - W00i*ri;  b00i += W00r*ri + W00i*rr;
            b01r += W01r*rr - W01i*ri;  b01i += W01r*ri + W01i*rr;
            b10r += W10r*rr - W10i*ri;  b10i += W10r*ri + W10i*rr;
            b11r += W11*rr;             b11i += W11*ri;
        }
    }

    // coef = 1 - i*t for l ; 1 + i*t for L-l
    float2 ar1 = woodbury_coef(a00r,a00i,a01r,a01i,a10r,a10i,a10i==0?0:a10i*0+a11r,a11i, -t);
    // (typo-proof: recompute properly below)
    ar1 = woodbury_coef(a00r,a00i,a01r,a01i,a10r,a10i,a11r,a11i, -t);
    float2 ar2 = woodbury_coef(b00r,b00i,b01r,b01i,b10r,b10i,b11r,b11i, +t);

    // Kf[l] = 0.5*(ar(l) + conj(ar(L-l))) ; fold in D-term (real constant)
    float2 kf = make_float2(0.5f*(ar1.x + ar2.x) + dterm, 0.5f*(ar1.y - ar2.y));
    Kf[(size_t)d*LL + ((l & 63)*64 + (l >> 6))] = kf;
}

// ---------------------------------------------------------------------------
// Kernel 2 (fused): per (b, d-pair): load x[:,2d2:2d2+2] as packed complex,
// forward FFT-4096 (four-step 64x64 in LDS), unpack/multiply-by-Kf/repack
// (two-for-one real conv), inverse FFT, write y[:,2d2:2d2+2] directly.
// D*x is already folded into Kf.
// ---------------------------------------------------------------------------
__global__ __launch_bounds__(256)
void s4_fftconv(const float* __restrict__ x, const float2* __restrict__ Kf,
                float* __restrict__ y)
{
    __shared__ float2 A[64][65];
    const int tid  = threadIdx.x;
    const int lane = tid & 63;
    const int wid  = tid >> 6;
    // XCD-aware swizzle: 8 consecutive-d2 blocks (which share y/x cache lines)
    // land on the same XCD.
    const int p  = ((blockIdx.x & 7) << 7) | (blockIdx.x >> 3);   // 1024 blocks
    const int b  = p >> 7;
    const int d2 = p & 127;

    const float2* xp = (const float2*)x + ((size_t)b*LL)*(DD/2) + d2;
    float2*       yp = (float2*)y       + ((size_t)b*LL)*(DD/2) + d2;

    // per-lane stage twiddles (forward): exp(-i*pi*j/m), j = lane&(m-1)
    float twc[6], tws[6];
#pragma unroll
    for (int s = 0; s < 6; ++s) {
        int m = 32 >> s;
        int j = lane & (m-1);
        float ang = -(float)M_PI * (float)j / (float)m;
        sincosf(ang, &tws[s], &twc[s]);
    }

    // load packed column: z[n] = x[n][2d2] + i x[n][2d2+1]; n=n1*64+n2 at A[n1][n2]
#pragma unroll
    for (int i = 0; i < 16; ++i) {
        int n = tid + 256*i;
        A[n>>6][n&63] = xp[(size_t)n*(DD/2)];
    }
    __syncthreads();

    // forward: column FFTs over n1
#pragma unroll 4
    for (int c = 0; c < 16; ++c) {
        int col = wid*16 + c;
        float2 v = A[lane][col];
        v = fft64<false>(v, lane, twc, tws);
        A[rev6(lane)][col] = v;
    }
    __syncthreads();

    // twiddle W_4096^{-k1*n2} at [r][c], r=(tid>>6)+4i, c=tid&63 (recurrence)
    const float TW = -(float)(2.0*M_PI/4096.0);
    {
        const int c  = tid & 63;
        const int r0 = tid >> 6;
        float2 w, st;
        sincosf(TW * (float)(r0*c), &w.y,  &w.x);
        sincosf(TW * (float)(4*c),  &st.y, &st.x);
#pragma unroll
        for (int i = 0; i < 16; ++i) {
            int r = r0 + 4*i;
            A[r][c] = cmulf(A[r][c], w);
            w = cmulf(w, st);
        }
    }
    __syncthreads();

    // forward: row FFTs over n2 -> X[k1 + 64*k2] at A[k1][k2]
#pragma unroll 4
    for (int c = 0; c < 16; ++c) {
        int row = wid*16 + c;
        float2 v = A[row][lane];
        v = fft64<false>(v, lane, twc, tws);
        A[row][rev6(lane)] = v;
    }
    __syncthreads();

    // two-for-one unpack * Kf * repack:
    // Y[k]  = 0.5*( Z[k]*(Ke+Ko) + conj(Z[~k])*(Ke-Ko) )
    // Y[~k] = conj( 0.5*( conj(Z[~k])*(Ke+Ko) + Z[k]*(Ke-Ko) ) )
    {
        const float2* Keb = Kf + (size_t)(2*d2)  *LL;
        const float2* Kob = Kf + (size_t)(2*d2+1)*LL;
#pragma unroll
        for (int i = 0; i < 9; ++i) {
            int k = tid + (i << 8);
            if (k <= 2048) {
                int k1 = k & 63, k2 = k >> 6;
                int m1 = (64 - k1) & 63;
                int m2 = (k1 == 0) ? ((64 - k2) & 63) : (63 - k2);
                float2 Zk = A[k1][k2];
                float2 Zm = A[m1][m2];
                float2 Ke = Keb[k1*64 + k2];
                float2 Ko = Kob[k1*64 + k2];
                float2 S  = make_float2(Ke.x + Ko.x, Ke.y + Ko.y);
                float2 Df = make_float2(Ke.x - Ko.x, Ke.y - Ko.y);
                float2 cZm = make_float2(Zm.x, -Zm.y);
                float2 t0 = cmulf(Zk,  S);
                float2 t1 = cmulf(cZm, Df);
                float2 Yk = make_float2(0.5f*(t0.x + t1.x), 0.5f*(t0.y + t1.y));
                float2 t2 = cmulf(cZm, S);
                float2 t3 = cmulf(Zk,  Df);
                float2 Ym = make_float2(0.5f*(t2.x + t3.x), -0.5f*(t2.y + t3.y));
                A[k1][k2] = Yk;
                A[m1][m2] = Ym;
            }
        }
    }
    __syncthreads();

    // inverse: row FFTs over k2
#pragma unroll 4
    for (int c = 0; c < 16; ++c) {
        int row = wid*16 + c;
        float2 v = A[row][lane];
        v = fft64<true>(v, lane, twc, tws);
        A[row][rev6(lane)] = v;
    }
    __syncthreads();

    // twiddle conj: W_4096^{+k1*n2}
    {
        const int c  = tid & 63;
        const int r0 = tid >> 6;
        float2 w, st;
        sincosf(TW * (float)(r0*c), &w.y,  &w.x);
        sincosf(TW * (float)(4*c),  &st.y, &st.x);
        w.y = -w.y; st.y = -st.y;
#pragma unroll
        for (int i = 0; i < 16; ++i) {
            int r = r0 + 4*i;
            A[r][c] = cmulf(A[r][c], w);
            w = cmulf(w, st);
        }
    }
    __syncthreads();

    // inverse: column FFTs over k1 -> time sample n at A[n>>6][n&63]
#pragma unroll 4
    for (int c = 0; c < 16; ++c) {
        int col = wid*16 + c;
        float2 v = A[lane][col];
        v = fft64<true>(v, lane, twc, tws);
        A[rev6(lane)][col] = v;
    }
    __syncthreads();

    // y_even = Re, y_odd = Im (D*x already inside Kf)
    const float scale = 1.f/4096.f;
#pragma unroll
    for (int i = 0; i < 16; ++i) {
        int n = tid + 256*i;
        float2 v = A[n>>6][n&63];
        yp[(size_t)n*(DD/2)] = make_float2(v.x*scale, v.y*scale);
    }
}

extern "C" void kernel_launch(void* const* d_in, const int* in_sizes, int n_in,
                              void* d_out, int out_size, void* d_ws, size_t ws_size,
                              hipStream_t stream)
{
    (void)in_sizes; (void)n_in; (void)out_size; (void)ws_size;
    const float* x         = (const float*)d_in[0];
    const float* lam_ri    = (const float*)d_in[1];
    const float* P_ri      = (const float*)d_in[2];
    const float* B_ri      = (const float*)d_in[3];
    const float* C_ri      = (const float*)d_in[4];
    const float* Dp        = (const float*)d_in[5];
    const float* log_delta = (const float*)d_in[6];
    float* y = (float*)d_out;

    float2* Kf = (float2*)d_ws;   // DD * LL * 8B = 8 MB

    s4_cauchy_kf<<<dim3(9, DD), 256, 0, stream>>>(lam_ri, P_ri, B_ri, C_ri, Dp, log_delta, Kf);
    s4_fftconv<<<dim3(BB*DD/2), 256, 0, stream>>>(x, Kf, y);
}